// Round 6
// baseline (1743.634 us; speedup 1.0000x reference)
//
#include <hip/hip_runtime.h>

// GADBase diffusion: B=2, H=W=512, 128 fused diffuse+adjust steps in ONE
// persistent cooperative kernel. No grid barrier: tiles sync only with their
// 4 neighbors via agent-scope atomic edge buffers + per-tile flags.
// Each 64-lane WG owns a 32x32 tile in registers (lane = one 4x4 pool block).
constexpr int Hh = 512, Ww = 512, Bn = 2;
constexpr int SWs = 128;
constexpr float Lf = 0.24f;
constexpr float Kf = 0.03f;
constexpr float EPSf = 1e-8f;
constexpr int NSTEPS = 128;

constexpr int NPIX = Bn * Hh * Ww;        // 524288
constexpr int CVN  = Bn * (Hh - 1) * Ww;  // 523264

constexpr int TS = 32;                    // tile side
constexpr int TG = Ww / TS;               // 16 tiles per row/col
constexpr int NT = Bn * TG * TG;          // 512 tiles (one wave each)

__device__ __forceinline__ int clampi(int v, int lo, int hi) {
  return min(max(v, lo), hi);
}
__device__ __forceinline__ void est(unsigned* p, float v) {
  __hip_atomic_store(p, __float_as_uint(v), __ATOMIC_RELAXED,
                     __HIP_MEMORY_SCOPE_AGENT);
}
__device__ __forceinline__ float eld(const unsigned* p) {
  return __uint_as_float(__hip_atomic_load(p, __ATOMIC_RELAXED,
                                           __HIP_MEMORY_SCOPE_AGENT));
}

// edges layout: [parity][tile][dir][32] uints. dir: 0=top row(my row 0),
// 1=bottom row(my row 31), 2=left col(my col 0), 3=right col(my col 31).
__global__ __launch_bounds__(64) void gad_persistent(
    const float* __restrict__ ybic, const float* __restrict__ guide,
    float* __restrict__ ypred, float* __restrict__ cvout,
    float* __restrict__ chout, const float* __restrict__ source,
    const float* __restrict__ mask, unsigned* __restrict__ flags,
    unsigned* __restrict__ edges) {
  int wg = blockIdx.x;
  int b  = wg >> 8;                        // 256 tiles per image
  int t  = wg & 255;
  int ty = t >> 4, tx = t & 15;
  int lane = threadIdx.x;
  int by = lane >> 3, bx = lane & 7;       // block coords in 8x8 tile grid
  int gy0 = ty * TS + by * 4;              // block origin (always in-image)
  int gx0 = tx * TS + bx * 4;

  const size_t HW = (size_t)Hh * Ww;
  const float* Fc0 = ybic + (size_t)b * HW;
  const float* Fc1 = guide + ((size_t)b * 3 + 0) * HW;
  const float* Fc2 = guide + ((size_t)b * 3 + 1) * HW;
  const float* Fc3 = guide + ((size_t)b * 3 + 2) * HW;

  // ---------------- prologue: cv/ch coefficients (and d_out cv/ch) --------
  float cvk[5][4];                         // edge rows gy0-1..gy0+3
  float chk[4][5];                         // edge cols gx0-1..gx0+3
#pragma unroll
  for (int k = 0; k < 5; ++k)
#pragma unroll
    for (int c = 0; c < 4; ++c) cvk[k][c] = 0.0f;
#pragma unroll
  for (int r = 0; r < 4; ++r)
#pragma unroll
    for (int j = 0; j < 5; ++j) chk[r][j] = 0.0f;

  const float* Fp[4] = {Fc0, Fc1, Fc2, Fc3};
#pragma unroll
  for (int chn = 0; chn < 4; ++chn) {
    const float* F = Fp[chn];
    float4 Rp = *reinterpret_cast<const float4*>(
        &F[(size_t)clampi(gy0 - 1, 0, Hh - 1) * Ww + gx0]);
#pragma unroll
    for (int j = 1; j <= 5; ++j) {
      int ro = clampi(gy0 - 1 + j, 0, Hh - 1);
      float4 Rc = *reinterpret_cast<const float4*>(&F[(size_t)ro * Ww + gx0]);
      int k = j - 1;                       // vertical edge gy0-1+k
      cvk[k][0] += fabsf(Rc.x - Rp.x);
      cvk[k][1] += fabsf(Rc.y - Rp.y);
      cvk[k][2] += fabsf(Rc.z - Rp.z);
      cvk[k][3] += fabsf(Rc.w - Rp.w);
      if (j <= 4) {                        // horizontal edges on row gy0+j-1
        int r = j - 1;
        int row = gy0 + r;
        float lv = (gx0 > 0) ? F[(size_t)row * Ww + gx0 - 1] : Rc.x;
        float rv = (gx0 + 4 < Ww) ? F[(size_t)row * Ww + gx0 + 4] : Rc.w;
        chk[r][0] += fabsf(Rc.x - lv);
        chk[r][1] += fabsf(Rc.y - Rc.x);
        chk[r][2] += fabsf(Rc.z - Rc.y);
        chk[r][3] += fabsf(Rc.w - Rc.z);
        chk[r][4] += fabsf(rv - Rc.w);
      }
      Rp = Rc;
    }
  }
  const float invk2 = 1.0f / (Kf * Kf);
#pragma unroll
  for (int k = 0; k < 5; ++k) {
    int ro = gy0 - 1 + k;
    bool val = (ro >= 0 && ro < Hh - 1);
#pragma unroll
    for (int c = 0; c < 4; ++c) {
      float m = 0.25f * cvk[k][c];
      cvk[k][c] = val ? 1.0f / (1.0f + m * m * invk2) : 0.0f;
    }
  }
#pragma unroll
  for (int r = 0; r < 4; ++r)
#pragma unroll
    for (int j = 0; j < 5; ++j) {
      int e = gx0 - 1 + j;
      bool val = (e >= 0 && e < Ww - 1);
      float m = 0.25f * chk[r][j];
      chk[r][j] = val ? 1.0f / (1.0f + m * m * invk2) : 0.0f;
    }
  // write raw cv/ch outputs (disjoint coverage: each thread rows/cols of own block)
#pragma unroll
  for (int k = 1; k < 5; ++k) {
    int ro = gy0 - 1 + k;
    if (ro < Hh - 1)
      *reinterpret_cast<float4*>(&cvout[(size_t)b * (Hh - 1) * Ww + (size_t)ro * Ww + gx0]) =
          make_float4(cvk[k][0], cvk[k][1], cvk[k][2], cvk[k][3]);
  }
#pragma unroll
  for (int r = 0; r < 4; ++r)
#pragma unroll
    for (int j = 1; j < 5; ++j) {
      int e = gx0 - 1 + j;
      if (e < Ww - 1)
        chout[((size_t)b * Hh + gy0 + r) * (Ww - 1) + e] = chk[r][j];
    }
  // fold diffusion rate
#pragma unroll
  for (int k = 0; k < 5; ++k)
#pragma unroll
    for (int c = 0; c < 4; ++c) cvk[k][c] *= Lf;
#pragma unroll
  for (int r = 0; r < 4; ++r)
#pragma unroll
    for (int j = 0; j < 5; ++j) chk[r][j] *= Lf;

  // ---------------- own 4x4 block + initial neighbor pixels ---------------
  float I[4][4];
#pragma unroll
  for (int r = 0; r < 4; ++r) {
    float4 t4 = *reinterpret_cast<const float4*>(&Fc0[(size_t)(gy0 + r) * Ww + gx0]);
    I[r][0] = t4.x; I[r][1] = t4.y; I[r][2] = t4.z; I[r][3] = t4.w;
  }
  float nT[4], nB[4], nL[4], nR[4];
  {
    int rT = clampi(gy0 - 1, 0, Hh - 1), rB = clampi(gy0 + 4, 0, Hh - 1);
    float4 t4 = *reinterpret_cast<const float4*>(&Fc0[(size_t)rT * Ww + gx0]);
    nT[0] = t4.x; nT[1] = t4.y; nT[2] = t4.z; nT[3] = t4.w;
    t4 = *reinterpret_cast<const float4*>(&Fc0[(size_t)rB * Ww + gx0]);
    nB[0] = t4.x; nB[1] = t4.y; nB[2] = t4.z; nB[3] = t4.w;
    int cL = clampi(gx0 - 1, 0, Ww - 1), cR = clampi(gx0 + 4, 0, Ww - 1);
#pragma unroll
    for (int r = 0; r < 4; ++r) {
      nL[r] = Fc0[(size_t)(gy0 + r) * Ww + cL];
      nR[r] = Fc0[(size_t)(gy0 + r) * Ww + cR];
    }
  }

  int sidx = (b * SWs + (gy0 >> 2)) * SWs + (gx0 >> 2);
  float srcv = source[sidx];
  bool mskv = mask[sidx] > 0.5f;

  // neighbor tile id for my poll slot (lane 0:up 1:down 2:left 3:right)
  int nbid = -1;
  if (lane == 0 && ty > 0)      nbid = wg - TG;
  if (lane == 1 && ty < TG - 1) nbid = wg + TG;
  if (lane == 2 && tx > 0)      nbid = wg - 1;
  if (lane == 3 && tx < TG - 1) nbid = wg + 1;

  // ---------------- 128 diffusion+adjust steps ----------------------------
  for (int s = 0; s < NSTEPS; ++s) {
    float V[4][4];
    float sum = 0.0f;
#pragma unroll
    for (int r = 0; r < 4; ++r)
#pragma unroll
      for (int c = 0; c < 4; ++c) {
        float cc = I[r][c];
        float up = (r == 0) ? nT[c] : I[r - 1][c];
        float dn = (r == 3) ? nB[c] : I[r + 1][c];
        float lf = (c == 0) ? nL[r] : I[r][c - 1];
        float rt = (c == 3) ? nR[r] : I[r][c + 1];
        float acc = cc + cvk[r + 1][c] * (dn - cc) - cvk[r][c] * (cc - up)
                       + chk[r][c + 1] * (rt - cc) - chk[r][c] * (cc - lf);
        V[r][c] = acc;
        sum += acc;
      }
    float ratio = mskv ? 1.0f : srcv / (sum * 0.0625f + EPSf);
#pragma unroll
    for (int r = 0; r < 4; ++r)
#pragma unroll
      for (int c = 0; c < 4; ++c) I[r][c] = V[r][c] * ratio;

    if (s == NSTEPS - 1) break;

    // --- publish tile-border pixels (agent-scope; double-buffer by parity)
    int par = s & 1;
    unsigned* eb = edges + ((size_t)(par * NT + wg) * 4) * 32;
    if (by == 0) {
#pragma unroll
      for (int c = 0; c < 4; ++c) est(eb + 0 * 32 + bx * 4 + c, I[0][c]);
    }
    if (by == 7) {
#pragma unroll
      for (int c = 0; c < 4; ++c) est(eb + 1 * 32 + bx * 4 + c, I[3][c]);
    }
    if (bx == 0) {
#pragma unroll
      for (int r = 0; r < 4; ++r) est(eb + 2 * 32 + by * 4 + r, I[r][0]);
    }
    if (bx == 7) {
#pragma unroll
      for (int r = 0; r < 4; ++r) est(eb + 3 * 32 + by * 4 + r, I[r][3]);
    }
    if (lane == 0)
      __hip_atomic_store(&flags[wg], (unsigned)(s + 1), __ATOMIC_RELEASE,
                         __HIP_MEMORY_SCOPE_AGENT);

    // --- wait for the 4 neighbors to publish step s (whole wave spins) ---
    if (nbid >= 0) {
      while (__hip_atomic_load(&flags[nbid], __ATOMIC_ACQUIRE,
                               __HIP_MEMORY_SCOPE_AGENT) < (unsigned)(s + 1))
        __builtin_amdgcn_s_sleep(2);
    }

    // --- gather neighbor pixels for next step ---------------------------
    // interior: cross-lane from neighbor blocks in the same wave
    float sT0 = __shfl(I[3][0], lane - 8), sT1 = __shfl(I[3][1], lane - 8);
    float sT2 = __shfl(I[3][2], lane - 8), sT3 = __shfl(I[3][3], lane - 8);
    float sB0 = __shfl(I[0][0], lane + 8), sB1 = __shfl(I[0][1], lane + 8);
    float sB2 = __shfl(I[0][2], lane + 8), sB3 = __shfl(I[0][3], lane + 8);
    float sL0 = __shfl(I[0][3], lane - 1), sL1 = __shfl(I[1][3], lane - 1);
    float sL2 = __shfl(I[2][3], lane - 1), sL3 = __shfl(I[3][3], lane - 1);
    float sR0 = __shfl(I[0][0], lane + 1), sR1 = __shfl(I[1][0], lane + 1);
    float sR2 = __shfl(I[2][0], lane + 1), sR3 = __shfl(I[3][0], lane + 1);

    if (by > 0) {
      nT[0] = sT0; nT[1] = sT1; nT[2] = sT2; nT[3] = sT3;
    } else if (ty > 0) {
      const unsigned* nb = edges + ((size_t)(par * NT + (wg - TG)) * 4 + 1) * 32;
#pragma unroll
      for (int c = 0; c < 4; ++c) nT[c] = eld(nb + bx * 4 + c);
    }
    if (by < 7) {
      nB[0] = sB0; nB[1] = sB1; nB[2] = sB2; nB[3] = sB3;
    } else if (ty < TG - 1) {
      const unsigned* nb = edges + ((size_t)(par * NT + (wg + TG)) * 4 + 0) * 32;
#pragma unroll
      for (int c = 0; c < 4; ++c) nB[c] = eld(nb + bx * 4 + c);
    }
    if (bx > 0) {
      nL[0] = sL0; nL[1] = sL1; nL[2] = sL2; nL[3] = sL3;
    } else if (tx > 0) {
      const unsigned* nb = edges + ((size_t)(par * NT + (wg - 1)) * 4 + 3) * 32;
#pragma unroll
      for (int r = 0; r < 4; ++r) nL[r] = eld(nb + by * 4 + r);
    }
    if (bx < 7) {
      nR[0] = sR0; nR[1] = sR1; nR[2] = sR2; nR[3] = sR3;
    } else if (tx < TG - 1) {
      const unsigned* nb = edges + ((size_t)(par * NT + (wg + 1)) * 4 + 2) * 32;
#pragma unroll
      for (int r = 0; r < 4; ++r) nR[r] = eld(nb + by * 4 + r);
    }
    // image-border directions: keep initial clamped values (coeff is 0)
  }

  // ---------------- final write -------------------------------------------
  float* Y = ypred + (size_t)b * HW;
#pragma unroll
  for (int r = 0; r < 4; ++r)
    *reinterpret_cast<float4*>(&Y[(size_t)(gy0 + r) * Ww + gx0]) =
        make_float4(I[r][0], I[r][1], I[r][2], I[r][3]);
}

// ---------------------------------------------------------------------------
extern "C" void kernel_launch(void* const* d_in, const int* in_sizes, int n_in,
                              void* d_out, int out_size, void* d_ws, size_t ws_size,
                              hipStream_t stream) {
  const float* guide  = (const float*)d_in[0];
  const float* ybic   = (const float*)d_in[1];
  const float* source = (const float*)d_in[2];
  const float* mask   = (const float*)d_in[3];

  float* out   = (float*)d_out;
  float* ypred = out;                 // 524288
  float* cv    = out + NPIX;          // 523264
  float* ch    = out + NPIX + CVN;    // 523264

  unsigned* flags = (unsigned*)d_ws;                      // NT uints
  unsigned* edges = (unsigned*)((char*)d_ws + 4096);      // 2*NT*4*32 uints

  hipMemsetAsync(d_ws, 0, 4096, stream);                  // zero flags

  void* args[] = {(void*)&ybic, (void*)&guide, (void*)&ypred, (void*)&cv,
                  (void*)&ch,   (void*)&source, (void*)&mask,
                  (void*)&flags, (void*)&edges};
  hipLaunchCooperativeKernel((const void*)gad_persistent, dim3(NT), dim3(64),
                             args, 0, stream);
}

// Round 8
// 504.035 us; speedup vs baseline: 3.4594x; 3.4594x over previous
//
#include <hip/hip_runtime.h>

// GADBase diffusion: B=2, H=W=512, 128 iterations of fused diffuse+adjust.
// Register-resident temporal blocking, KS=8 steps/launch: each of 576 threads
// owns one 4x4 block of a 96x96 region around a 32x32 output tile; per step
// only block edges go through LDS. 16 diffusion launches + 1 cvch = 17 total.
constexpr int Hh = 512, Ww = 512, Bn = 2;
constexpr int SWs = 128;
constexpr float Lf = 0.24f;
constexpr float Kf = 0.03f;
constexpr float EPSf = 1e-8f;
constexpr int NSTEPS = 128;

constexpr int NPIX = Bn * Hh * Ww;        // 524288
constexpr int CVN  = Bn * (Hh - 1) * Ww;  // 523264

constexpr int OT = 32;                    // output tile side
constexpr int KS = 8;                     // steps per launch
constexpr int HALO = 4 * KS;              // 32
constexpr int G = (OT + 2 * HALO) / 4;    // 24x24 block grid per region
constexpr int NB = G * G;                 // 576 blocks == threads
constexpr int REC = 20;                   // edge record stride (dwords)
constexpr int NWG = Bn * (Hh / OT) * (Ww / OT);  // 512
constexpr int NLAUNCH = NSTEPS / KS;      // 16

__device__ __forceinline__ int clampi(int v, int lo, int hi) {
  return min(max(v, lo), hi);
}
// Linear record offset (dwords). REC=20 staggers bank bases: t*20 mod 32
// cycles {0,20,8,28,16,4,24,12}, so adjacent lanes' b128 reads hit disjoint
// bank quartets. NOTE: records use 16 of 20 dwords; any nonzero per-record
// shift >=4 dwords collides with the next record (round-7 bug) - keep linear.
__device__ __forceinline__ int recof(int t) { return t * REC; }

// ---------------------------------------------------------------------------
// Kernel 1: edge-stopping coefficients cv, ch (once, into d_out slots).
// ---------------------------------------------------------------------------
__global__ __launch_bounds__(256) void cvch_kernel(
    const float* __restrict__ img, const float* __restrict__ guide,
    float* __restrict__ cv, float* __restrict__ ch) {
  int idx = blockIdx.x * blockDim.x + threadIdx.x;
  if (idx >= NPIX) return;
  int x = idx & (Ww - 1);
  int y = (idx >> 9) & (Hh - 1);
  int b = idx >> 18;
  const float inv_k2 = 1.0f / (Kf * Kf);
  const float* f0 = img + (size_t)b * Hh * Ww;
  const float* g0 = guide + (size_t)b * 3 * Hh * Ww;
  const float* g1 = g0 + Hh * Ww;
  const float* g2 = g1 + Hh * Ww;
  int p = y * Ww + x;
  float c0 = f0[p], c1 = g0[p], c2 = g1[p], c3 = g2[p];
  if (y < Hh - 1) {
    int q = p + Ww;
    float m = (fabsf(f0[q] - c0) + fabsf(g0[q] - c1) +
               fabsf(g1[q] - c2) + fabsf(g2[q] - c3)) * 0.25f;
    cv[(b * (Hh - 1) + y) * Ww + x] = 1.0f / (1.0f + m * m * inv_k2);
  }
  if (x < Ww - 1) {
    int q = p + 1;
    float m = (fabsf(f0[q] - c0) + fabsf(g0[q] - c1) +
               fabsf(g1[q] - c2) + fabsf(g2[q] - c3)) * 0.25f;
    ch[(b * Hh + y) * (Ww - 1) + x] = 1.0f / (1.0f + m * m * inv_k2);
  }
}

// ---------------------------------------------------------------------------
// Kernel 2: 8 diffusion+adjust steps per launch, block state in registers.
// 576 threads = all 24x24 blocks of the 96x96 region (1:1). Per step:
// <=4 ds_write_b128 + 4 ds_read_b128 (precomputed addresses).
// Shrinking active set: publish at step s gated to [s+1, G-1-s)^2, which
// exactly covers readers [s+2, G-2-s)^2 at step s+1; the final step's valid
// central 8x8 blocks = the 32x32 output tile.
// Off-image pixels are decoupled (boundary-crossing coefficients are 0) and
// stay finite; rim blocks may hold garbage but are never consumed.
// ---------------------------------------------------------------------------
__global__ __launch_bounds__(576) void diffuse8_kernel(
    const float* __restrict__ src, float* __restrict__ dst,
    const float* __restrict__ cv, const float* __restrict__ ch,
    const float* __restrict__ source, const float* __restrict__ mask) {
  __shared__ __align__(16) float ebuf[NB * REC];  // 45 KB

  int wg = blockIdx.x;
  int b  = wg >> 8;                        // 256 tiles per image
  int t  = wg & 255;
  int Ty0 = (t >> 4) * OT;
  int Tx0 = (t & 15) * OT;

  int tid = threadIdx.x;
  int by = tid / G, bx = tid - by * G;
  int gy0 = Ty0 - HALO + 4 * by;           // block origin (may be off-image)
  int gx0 = Tx0 - HALO + 4 * bx;

  // step-invariant LDS addresses (rim clamps read own record/garbage; those
  // lanes' values are never consumed)
  float* pMy = ebuf + recof(tid);
  const float* pU = ebuf + recof(by > 0     ? tid - G : tid) + 4;  // up's bottom
  const float* pD = ebuf + recof(by < G - 1 ? tid + G : tid) + 0;  // down's top
  const float* pL = ebuf + recof(bx > 0     ? tid - 1 : tid) + 12; // left's right
  const float* pR = ebuf + recof(bx < G - 1 ? tid + 1 : tid) + 8;  // right's left

  const size_t ib = (size_t)b * Hh * Ww;
  const float* S = src + ib;
  float* D = dst + ib;
  const float* cvb = cv + (size_t)b * (Hh - 1) * Ww;
  const float* chb = ch + (size_t)b * Hh * (Ww - 1);

  auto ld4 = [&](int gy, int gx) -> float4 {
    gy = clampi(gy, 0, Hh - 1);
    if (gx < 0)      { float v = S[gy * Ww];          return make_float4(v, v, v, v); }
    if (gx > Ww - 4) { float v = S[gy * Ww + Ww - 1]; return make_float4(v, v, v, v); }
    return *reinterpret_cast<const float4*>(&S[gy * Ww + gx]);
  };

  // --- own 4x4 block + initial neighbor edges (time 0, from global) ------
  float I[4][4];
#pragma unroll
  for (int r = 0; r < 4; ++r) {
    float4 t4 = ld4(gy0 + r, gx0);
    I[r][0] = t4.x; I[r][1] = t4.y; I[r][2] = t4.z; I[r][3] = t4.w;
  }
  float nT[4], nB[4], nL[4], nR[4];
  {
    float4 t4 = ld4(gy0 - 1, gx0);
    nT[0] = t4.x; nT[1] = t4.y; nT[2] = t4.z; nT[3] = t4.w;
    t4 = ld4(gy0 + 4, gx0);
    nB[0] = t4.x; nB[1] = t4.y; nB[2] = t4.z; nB[3] = t4.w;
    int cL = clampi(gx0 - 1, 0, Ww - 1), cR = clampi(gx0 + 4, 0, Ww - 1);
#pragma unroll
    for (int r = 0; r < 4; ++r) {
      int gy = clampi(gy0 + r, 0, Hh - 1);
      nL[r] = S[gy * Ww + cL];
      nR[r] = S[gy * Ww + cR];
    }
  }

  // --- step-invariant coefficients (L folded in; boundary edges -> 0) ----
  float cvk[5][4];                         // edge rows gy0-1 .. gy0+3
#pragma unroll
  for (int k = 0; k < 5; ++k) {
    int ro = gy0 - 1 + k;
    if (ro < 0 || ro > Hh - 2) {
      cvk[k][0] = cvk[k][1] = cvk[k][2] = cvk[k][3] = 0.0f;
    } else if (gx0 < 0) {
      float v = Lf * cvb[ro * Ww];
      cvk[k][0] = cvk[k][1] = cvk[k][2] = cvk[k][3] = v;
    } else if (gx0 > Ww - 4) {
      float v = Lf * cvb[ro * Ww + Ww - 1];
      cvk[k][0] = cvk[k][1] = cvk[k][2] = cvk[k][3] = v;
    } else {
      float4 t4 = *reinterpret_cast<const float4*>(&cvb[ro * Ww + gx0]);
      cvk[k][0] = Lf * t4.x; cvk[k][1] = Lf * t4.y;
      cvk[k][2] = Lf * t4.z; cvk[k][3] = Lf * t4.w;
    }
  }
  float chk[4][5];                         // edge cols gx0-1 .. gx0+3
#pragma unroll
  for (int r = 0; r < 4; ++r) {
    int ri = clampi(gy0 + r, 0, Hh - 1);
#pragma unroll
    for (int j = 0; j < 5; ++j) {
      int e = gx0 - 1 + j;
      chk[r][j] = (e >= 0 && e <= Ww - 2) ? Lf * chb[ri * (Ww - 1) + e] : 0.0f;
    }
  }

  int sy = clampi(gy0 >> 2, 0, SWs - 1);
  int sx = clampi(gx0 >> 2, 0, SWs - 1);
  int sidx = (b * SWs + sy) * SWs + sx;
  float srcv = source[sidx];
  bool mskv = mask[sidx] > 0.5f;

#pragma unroll
  for (int s = 0; s < KS; ++s) {
    if (s > 0) {
      __syncthreads();
      float4 t4;
      t4 = *reinterpret_cast<const float4*>(pU);
      nT[0] = t4.x; nT[1] = t4.y; nT[2] = t4.z; nT[3] = t4.w;
      t4 = *reinterpret_cast<const float4*>(pD);
      nB[0] = t4.x; nB[1] = t4.y; nB[2] = t4.z; nB[3] = t4.w;
      t4 = *reinterpret_cast<const float4*>(pL);
      nL[0] = t4.x; nL[1] = t4.y; nL[2] = t4.z; nL[3] = t4.w;
      t4 = *reinterpret_cast<const float4*>(pR);
      nR[0] = t4.x; nR[1] = t4.y; nR[2] = t4.z; nR[3] = t4.w;
    }

    float V[4][4];
    float sum = 0.0f;
#pragma unroll
    for (int r = 0; r < 4; ++r)
#pragma unroll
      for (int c = 0; c < 4; ++c) {
        float cc = I[r][c];
        float up = (r == 0) ? nT[c] : I[r - 1][c];
        float dn = (r == 3) ? nB[c] : I[r + 1][c];
        float lf = (c == 0) ? nL[r] : I[r][c - 1];
        float rt = (c == 3) ? nR[r] : I[r][c + 1];
        float acc = cc + cvk[r + 1][c] * (dn - cc) - cvk[r][c] * (cc - up)
                       + chk[r][c + 1] * (rt - cc) - chk[r][c] * (cc - lf);
        V[r][c] = acc;
        sum += acc;
      }
    float ratio = mskv ? 1.0f : srcv / (sum * 0.0625f + EPSf);
#pragma unroll
    for (int r = 0; r < 4; ++r)
#pragma unroll
      for (int c = 0; c < 4; ++c) I[r][c] = V[r][c] * ratio;

    if (s == KS - 1) {
      // central 8x8 blocks == the 32x32 output tile
      if (by >= KS && by < G - KS && bx >= KS && bx < G - KS) {
#pragma unroll
        for (int r = 0; r < 4; ++r)
          *reinterpret_cast<float4*>(&D[(gy0 + r) * Ww + gx0]) =
              make_float4(I[r][0], I[r][1], I[r][2], I[r][3]);
      }
    } else {
      __syncthreads();
      if (by > s && by < G - 1 - s && bx > s && bx < G - 1 - s) {
        *reinterpret_cast<float4*>(pMy + 0) =
            make_float4(I[0][0], I[0][1], I[0][2], I[0][3]);   // top row
        *reinterpret_cast<float4*>(pMy + 4) =
            make_float4(I[3][0], I[3][1], I[3][2], I[3][3]);   // bottom row
        *reinterpret_cast<float4*>(pMy + 8) =
            make_float4(I[0][0], I[1][0], I[2][0], I[3][0]);   // left col
        *reinterpret_cast<float4*>(pMy + 12) =
            make_float4(I[0][3], I[1][3], I[2][3], I[3][3]);   // right col
      }
    }
  }
}

// ---------------------------------------------------------------------------
// Fallback (small ws): one launch per step.
// ---------------------------------------------------------------------------
constexpr int FT = 32;
__global__ __launch_bounds__(64) void step_kernel(
    const float* __restrict__ src, float* __restrict__ dst,
    const float* __restrict__ cv, const float* __restrict__ ch,
    const float* __restrict__ source, const float* __restrict__ mask) {
  __shared__ float sIl[FT + 2][FT + 3];
  int b = blockIdx.z;
  int ty0 = blockIdx.y * FT, tx0 = blockIdx.x * FT;
  const float* I = src + (size_t)b * Hh * Ww;
  int tid = threadIdx.x;
  for (int i = tid; i < (FT + 2) * (FT + 2); i += 64) {
    int ly = i / (FT + 2), lx = i % (FT + 2);
    int gy = max(0, min(Hh - 1, ty0 + ly - 1));
    int gx = max(0, min(Ww - 1, tx0 + lx - 1));
    sIl[ly][lx] = I[gy * Ww + gx];
  }
  __syncthreads();
  int bby = tid >> 3, bbx = tid & 7;
  int py0 = bby * 4, px0 = bbx * 4;
  int gy0 = ty0 + py0, gx0 = tx0 + px0;
  const float* cvb = cv + (size_t)b * (Hh - 1) * Ww;
  const float* chb = ch + (size_t)b * Hh * (Ww - 1);
  float v[4][4]; float sum = 0.0f;
#pragma unroll
  for (int dy = 0; dy < 4; ++dy) {
    int y = gy0 + dy, ly = py0 + dy + 1;
#pragma unroll
    for (int dx = 0; dx < 4; ++dx) {
      int x = gx0 + dx, lx = px0 + dx + 1;
      float cc = sIl[ly][lx];
      float acc = cc;
      if (y < Hh - 1) acc += Lf * cvb[y * Ww + x] * (sIl[ly + 1][lx] - cc);
      if (y > 0)      acc -= Lf * cvb[(y - 1) * Ww + x] * (cc - sIl[ly - 1][lx]);
      if (x < Ww - 1) acc += Lf * chb[y * (Ww - 1) + x] * (sIl[ly][lx + 1] - cc);
      if (x > 0)      acc -= Lf * chb[y * (Ww - 1) + x - 1] * (cc - sIl[ly][lx - 1]);
      v[dy][dx] = acc; sum += acc;
    }
  }
  int sidx = (b * SWs + (gy0 >> 2)) * SWs + (gx0 >> 2);
  float ratio = (mask[sidx] > 0.5f) ? 1.0f : source[sidx] / (sum * 0.0625f + EPSf);
  float* D = dst + (size_t)b * Hh * Ww;
#pragma unroll
  for (int dy = 0; dy < 4; ++dy)
    *reinterpret_cast<float4*>(&D[(gy0 + dy) * Ww + gx0]) =
        make_float4(v[dy][0] * ratio, v[dy][1] * ratio,
                    v[dy][2] * ratio, v[dy][3] * ratio);
}

// ---------------------------------------------------------------------------
extern "C" void kernel_launch(void* const* d_in, const int* in_sizes, int n_in,
                              void* d_out, int out_size, void* d_ws, size_t ws_size,
                              hipStream_t stream) {
  const float* guide  = (const float*)d_in[0];
  const float* ybic   = (const float*)d_in[1];
  const float* source = (const float*)d_in[2];
  const float* mask   = (const float*)d_in[3];

  float* out   = (float*)d_out;
  float* ypred = out;                 // 524288
  float* cv    = out + NPIX;          // 523264
  float* ch    = out + NPIX + CVN;    // 523264

  cvch_kernel<<<dim3((NPIX + 255) / 256), dim3(256), 0, stream>>>(ybic, guide, cv, ch);

  if (ws_size >= (size_t)2 * NPIX * sizeof(float)) {
    float* wsb0 = (float*)d_ws;
    float* wsb1 = wsb0 + NPIX;
    const float* sp = ybic;
    for (int l = 0; l < NLAUNCH; ++l) {
      float* dp = (l == NLAUNCH - 1) ? ypred : ((l & 1) ? wsb1 : wsb0);
      diffuse8_kernel<<<dim3(NWG), dim3(NB), 0, stream>>>(sp, dp, cv, ch,
                                                          source, mask);
      sp = dp;
    }
  } else {
    float* wsbuf = (float*)d_ws;
    dim3 grid(Ww / FT, Hh / FT, Bn);
    const float* sp = ybic;
    for (int it = 0; it < NSTEPS; ++it) {
      float* dp = (it & 1) ? ypred : wsbuf;
      step_kernel<<<grid, dim3(64), 0, stream>>>(sp, dp, cv, ch, source, mask);
      sp = dp;
    }
  }
}

// Round 9
// 371.593 us; speedup vs baseline: 4.6923x; 1.3564x over previous
//
#include <hip/hip_runtime.h>

// GADBase diffusion: B=2, H=W=512, 128 iterations of fused diffuse+adjust.
// Register-resident temporal blocking, KS=7 steps/launch: 512 threads (8
// waves, 2 waves/SIMD, __launch_bounds__ caps VGPR<=128 so 2 WG/CU => 16
// waves/CU), each owning one 4x4 block of an 88x88 region (22x22 blocks, 484
// active threads) around a 32x32 output tile. Per step only block edges go
// through LDS. 18x7 + 1x2 steps -> 19 diffuse launches + 1 cvch = 20 total.
constexpr int Hh = 512, Ww = 512, Bn = 2;
constexpr int SWs = 128;
constexpr float Lf = 0.24f;
constexpr float Kf = 0.03f;
constexpr float EPSf = 1e-8f;
constexpr int NSTEPS = 128;

constexpr int NPIX = Bn * Hh * Ww;        // 524288
constexpr int CVN  = Bn * (Hh - 1) * Ww;  // 523264

constexpr int OT = 32;                    // output tile side
constexpr int KS = 7;                     // max steps per launch
constexpr int HALO = 4 * KS;              // 28
constexpr int G = (OT + 2 * HALO) / 4;    // 22x22 block grid per region
constexpr int NB = G * G;                 // 484 blocks
constexpr int NTHR = 512;                 // 8 waves
constexpr int REC = 20;                   // edge record stride (dwords)
constexpr int NWG = Bn * (Hh / OT) * (Ww / OT);  // 512

__device__ __forceinline__ int clampi(int v, int lo, int hi) {
  return min(max(v, lo), hi);
}
// Linear record offset. REC=20 staggers bank bases (t*20 mod 32 cycles
// {0,20,8,28,16,4,24,12}). Records use 16 of 20 dwords; NO per-record shift
// (round-7 lesson: any shift >=4 dwords collides with the next record).
__device__ __forceinline__ int recof(int t) { return t * REC; }

// ---------------------------------------------------------------------------
// Kernel 1: edge-stopping coefficients cv, ch (once, into d_out slots).
// ---------------------------------------------------------------------------
__global__ __launch_bounds__(256) void cvch_kernel(
    const float* __restrict__ img, const float* __restrict__ guide,
    float* __restrict__ cv, float* __restrict__ ch) {
  int idx = blockIdx.x * blockDim.x + threadIdx.x;
  if (idx >= NPIX) return;
  int x = idx & (Ww - 1);
  int y = (idx >> 9) & (Hh - 1);
  int b = idx >> 18;
  const float inv_k2 = 1.0f / (Kf * Kf);
  const float* f0 = img + (size_t)b * Hh * Ww;
  const float* g0 = guide + (size_t)b * 3 * Hh * Ww;
  const float* g1 = g0 + Hh * Ww;
  const float* g2 = g1 + Hh * Ww;
  int p = y * Ww + x;
  float c0 = f0[p], c1 = g0[p], c2 = g1[p], c3 = g2[p];
  if (y < Hh - 1) {
    int q = p + Ww;
    float m = (fabsf(f0[q] - c0) + fabsf(g0[q] - c1) +
               fabsf(g1[q] - c2) + fabsf(g2[q] - c3)) * 0.25f;
    cv[(b * (Hh - 1) + y) * Ww + x] = 1.0f / (1.0f + m * m * inv_k2);
  }
  if (x < Ww - 1) {
    int q = p + 1;
    float m = (fabsf(f0[q] - c0) + fabsf(g0[q] - c1) +
               fabsf(g1[q] - c2) + fabsf(g2[q] - c3)) * 0.25f;
    ch[(b * Hh + y) * (Ww - 1) + x] = 1.0f / (1.0f + m * m * inv_k2);
  }
}

// ---------------------------------------------------------------------------
// Kernel 2: up to 7 diffusion+adjust steps per launch, block state in regs.
// Shrinking active set: publish at step s gated to (s, G-1-s)^2, which covers
// readers (s+1, G-2-s)^2 at step s+1; final central 8x8 blocks [KS, G-KS)^2 =
// the 32x32 output tile. Off-image pixels are decoupled (boundary-crossing
// coefficients exactly 0) and stay finite; stale/garbage block values are
// never consumed by the valid set.
// ---------------------------------------------------------------------------
__global__ __launch_bounds__(NTHR, 4) void diffuse7_kernel(
    const float* __restrict__ src, float* __restrict__ dst,
    const float* __restrict__ cv, const float* __restrict__ ch,
    const float* __restrict__ source, const float* __restrict__ mask,
    int nsteps) {
  __shared__ __align__(16) float ebuf[NB * REC];  // 38.7 KB

  int wg = blockIdx.x;
  int b  = wg >> 8;                        // 256 tiles per image
  int t  = wg & 255;
  int Ty0 = (t >> 4) * OT;
  int Tx0 = (t & 15) * OT;

  int tid = threadIdx.x;
  int tt = min(tid, NB - 1);               // idle threads alias block NB-1
  int by = tt / G, bx = tt - by * G;       // const divisor -> magic mul
  int gy0 = Ty0 - HALO + 4 * by;           // block origin (may be off-image)
  int gx0 = Tx0 - HALO + 4 * bx;

  // step-invariant LDS addresses (aliased/rim lanes never have their reads
  // consumed; all record indices stay in [0, NB))
  float* pMy = ebuf + recof(tt);
  const float* pU = ebuf + recof(by > 0     ? tt - G : tt) + 4;  // up's bottom
  const float* pD = ebuf + recof(by < G - 1 ? tt + G : tt) + 0;  // down's top
  const float* pL = ebuf + recof(bx > 0     ? tt - 1 : tt) + 12; // left's right
  const float* pR = ebuf + recof(bx < G - 1 ? tt + 1 : tt) + 8;  // right's left

  const size_t ib = (size_t)b * Hh * Ww;
  const float* S = src + ib;
  float* D = dst + ib;
  const float* cvb = cv + (size_t)b * (Hh - 1) * Ww;
  const float* chb = ch + (size_t)b * Hh * (Ww - 1);

  auto ld4 = [&](int gy, int gx) -> float4 {
    gy = clampi(gy, 0, Hh - 1);
    if (gx < 0)      { float v = S[gy * Ww];          return make_float4(v, v, v, v); }
    if (gx > Ww - 4) { float v = S[gy * Ww + Ww - 1]; return make_float4(v, v, v, v); }
    return *reinterpret_cast<const float4*>(&S[gy * Ww + gx]);
  };

  // --- own 4x4 block + initial neighbor edges (time 0, from global) ------
  float I[4][4];
#pragma unroll
  for (int r = 0; r < 4; ++r) {
    float4 t4 = ld4(gy0 + r, gx0);
    I[r][0] = t4.x; I[r][1] = t4.y; I[r][2] = t4.z; I[r][3] = t4.w;
  }
  float nT[4], nB[4], nL[4], nR[4];
  {
    float4 t4 = ld4(gy0 - 1, gx0);
    nT[0] = t4.x; nT[1] = t4.y; nT[2] = t4.z; nT[3] = t4.w;
    t4 = ld4(gy0 + 4, gx0);
    nB[0] = t4.x; nB[1] = t4.y; nB[2] = t4.z; nB[3] = t4.w;
    int cL = clampi(gx0 - 1, 0, Ww - 1), cR = clampi(gx0 + 4, 0, Ww - 1);
#pragma unroll
    for (int r = 0; r < 4; ++r) {
      int gy = clampi(gy0 + r, 0, Hh - 1);
      nL[r] = S[gy * Ww + cL];
      nR[r] = S[gy * Ww + cR];
    }
  }

  // --- step-invariant coefficients (L folded in; boundary edges -> 0) ----
  float cvk[5][4];                         // edge rows gy0-1 .. gy0+3
#pragma unroll
  for (int k = 0; k < 5; ++k) {
    int ro = gy0 - 1 + k;
    if (ro < 0 || ro > Hh - 2) {
      cvk[k][0] = cvk[k][1] = cvk[k][2] = cvk[k][3] = 0.0f;
    } else if (gx0 < 0) {
      float v = Lf * cvb[ro * Ww];
      cvk[k][0] = cvk[k][1] = cvk[k][2] = cvk[k][3] = v;
    } else if (gx0 > Ww - 4) {
      float v = Lf * cvb[ro * Ww + Ww - 1];
      cvk[k][0] = cvk[k][1] = cvk[k][2] = cvk[k][3] = v;
    } else {
      float4 t4 = *reinterpret_cast<const float4*>(&cvb[ro * Ww + gx0]);
      cvk[k][0] = Lf * t4.x; cvk[k][1] = Lf * t4.y;
      cvk[k][2] = Lf * t4.z; cvk[k][3] = Lf * t4.w;
    }
  }
  float chk[4][5];                         // edge cols gx0-1 .. gx0+3
#pragma unroll
  for (int r = 0; r < 4; ++r) {
    int ri = clampi(gy0 + r, 0, Hh - 1);
#pragma unroll
    for (int j = 0; j < 5; ++j) {
      int e = gx0 - 1 + j;
      chk[r][j] = (e >= 0 && e <= Ww - 2) ? Lf * chb[ri * (Ww - 1) + e] : 0.0f;
    }
  }

  int sy = clampi(gy0 >> 2, 0, SWs - 1);
  int sx = clampi(gx0 >> 2, 0, SWs - 1);
  int sidx = (b * SWs + sy) * SWs + sx;
  float srcv = source[sidx];
  bool mskv = mask[sidx] > 0.5f;

#pragma unroll
  for (int s = 0; s < KS; ++s) {
    if (s >= nsteps) break;                // uniform; before any barrier
    if (s > 0) {
      __syncthreads();
      float4 t4;
      t4 = *reinterpret_cast<const float4*>(pU);
      nT[0] = t4.x; nT[1] = t4.y; nT[2] = t4.z; nT[3] = t4.w;
      t4 = *reinterpret_cast<const float4*>(pD);
      nB[0] = t4.x; nB[1] = t4.y; nB[2] = t4.z; nB[3] = t4.w;
      t4 = *reinterpret_cast<const float4*>(pL);
      nL[0] = t4.x; nL[1] = t4.y; nL[2] = t4.z; nL[3] = t4.w;
      t4 = *reinterpret_cast<const float4*>(pR);
      nR[0] = t4.x; nR[1] = t4.y; nR[2] = t4.z; nR[3] = t4.w;
    }

    // in-place stencil with row/col original-value delay (saves V[4][4] regs)
    float sum = 0.0f;
    float rowOrig[4];
#pragma unroll
    for (int r = 0; r < 4; ++r) {
      float leftOrig = 0.0f;
#pragma unroll
      for (int c = 0; c < 4; ++c) {
        float cc = I[r][c];
        float up = (r == 0) ? nT[c] : rowOrig[c];
        float dn = (r == 3) ? nB[c] : I[r + 1][c];
        float lf = (c == 0) ? nL[r] : leftOrig;
        float rt = (c == 3) ? nR[r] : I[r][c + 1];
        float acc = cc + cvk[r + 1][c] * (dn - cc) - cvk[r][c] * (cc - up)
                       + chk[r][c + 1] * (rt - cc) - chk[r][c] * (cc - lf);
        rowOrig[c] = cc;
        leftOrig = cc;
        I[r][c] = acc;
        sum += acc;
      }
    }
    float ratio = mskv ? 1.0f : srcv / (sum * 0.0625f + EPSf);
#pragma unroll
    for (int r = 0; r < 4; ++r)
#pragma unroll
      for (int c = 0; c < 4; ++c) I[r][c] *= ratio;

    if (s == nsteps - 1) {
      // central 8x8 blocks == the 32x32 output tile
      if (by >= KS && by < G - KS && bx >= KS && bx < G - KS) {
#pragma unroll
        for (int r = 0; r < 4; ++r)
          *reinterpret_cast<float4*>(&D[(gy0 + r) * Ww + gx0]) =
              make_float4(I[r][0], I[r][1], I[r][2], I[r][3]);
      }
    } else {
      __syncthreads();
      if (by > s && by < G - 1 - s && bx > s && bx < G - 1 - s) {
        *reinterpret_cast<float4*>(pMy + 0) =
            make_float4(I[0][0], I[0][1], I[0][2], I[0][3]);   // top row
        *reinterpret_cast<float4*>(pMy + 4) =
            make_float4(I[3][0], I[3][1], I[3][2], I[3][3]);   // bottom row
        *reinterpret_cast<float4*>(pMy + 8) =
            make_float4(I[0][0], I[1][0], I[2][0], I[3][0]);   // left col
        *reinterpret_cast<float4*>(pMy + 12) =
            make_float4(I[0][3], I[1][3], I[2][3], I[3][3]);   // right col
      }
    }
  }
}

// ---------------------------------------------------------------------------
// Fallback (small ws): one launch per step.
// ---------------------------------------------------------------------------
constexpr int FT = 32;
__global__ __launch_bounds__(64) void step_kernel(
    const float* __restrict__ src, float* __restrict__ dst,
    const float* __restrict__ cv, const float* __restrict__ ch,
    const float* __restrict__ source, const float* __restrict__ mask) {
  __shared__ float sIl[FT + 2][FT + 3];
  int b = blockIdx.z;
  int ty0 = blockIdx.y * FT, tx0 = blockIdx.x * FT;
  const float* I = src + (size_t)b * Hh * Ww;
  int tid = threadIdx.x;
  for (int i = tid; i < (FT + 2) * (FT + 2); i += 64) {
    int ly = i / (FT + 2), lx = i % (FT + 2);
    int gy = max(0, min(Hh - 1, ty0 + ly - 1));
    int gx = max(0, min(Ww - 1, tx0 + lx - 1));
    sIl[ly][lx] = I[gy * Ww + gx];
  }
  __syncthreads();
  int bby = tid >> 3, bbx = tid & 7;
  int py0 = bby * 4, px0 = bbx * 4;
  int gy0 = ty0 + py0, gx0 = tx0 + px0;
  const float* cvb = cv + (size_t)b * (Hh - 1) * Ww;
  const float* chb = ch + (size_t)b * Hh * (Ww - 1);
  float v[4][4]; float sum = 0.0f;
#pragma unroll
  for (int dy = 0; dy < 4; ++dy) {
    int y = gy0 + dy, ly = py0 + dy + 1;
#pragma unroll
    for (int dx = 0; dx < 4; ++dx) {
      int x = gx0 + dx, lx = px0 + dx + 1;
      float cc = sIl[ly][lx];
      float acc = cc;
      if (y < Hh - 1) acc += Lf * cvb[y * Ww + x] * (sIl[ly + 1][lx] - cc);
      if (y > 0)      acc -= Lf * cvb[(y - 1) * Ww + x] * (cc - sIl[ly - 1][lx]);
      if (x < Ww - 1) acc += Lf * chb[y * (Ww - 1) + x] * (sIl[ly][lx + 1] - cc);
      if (x > 0)      acc -= Lf * chb[y * (Ww - 1) + x - 1] * (cc - sIl[ly][lx - 1]);
      v[dy][dx] = acc; sum += acc;
    }
  }
  int sidx = (b * SWs + (gy0 >> 2)) * SWs + (gx0 >> 2);
  float ratio = (mask[sidx] > 0.5f) ? 1.0f : source[sidx] / (sum * 0.0625f + EPSf);
  float* D = dst + (size_t)b * Hh * Ww;
#pragma unroll
  for (int dy = 0; dy < 4; ++dy)
    *reinterpret_cast<float4*>(&D[(gy0 + dy) * Ww + gx0]) =
        make_float4(v[dy][0] * ratio, v[dy][1] * ratio,
                    v[dy][2] * ratio, v[dy][3] * ratio);
}

// ---------------------------------------------------------------------------
extern "C" void kernel_launch(void* const* d_in, const int* in_sizes, int n_in,
                              void* d_out, int out_size, void* d_ws, size_t ws_size,
                              hipStream_t stream) {
  const float* guide  = (const float*)d_in[0];
  const float* ybic   = (const float*)d_in[1];
  const float* source = (const float*)d_in[2];
  const float* mask   = (const float*)d_in[3];

  float* out   = (float*)d_out;
  float* ypred = out;                 // 524288
  float* cv    = out + NPIX;          // 523264
  float* ch    = out + NPIX + CVN;    // 523264

  cvch_kernel<<<dim3((NPIX + 255) / 256), dim3(256), 0, stream>>>(ybic, guide, cv, ch);

  if (ws_size >= (size_t)2 * NPIX * sizeof(float)) {
    float* wsb0 = (float*)d_ws;
    float* wsb1 = wsb0 + NPIX;
    const float* sp = ybic;
    int done = 0, l = 0;
    while (done < NSTEPS) {
      int ns = (NSTEPS - done >= KS) ? KS : (NSTEPS - done);  // 18x7 + 1x2
      bool lastL = (done + ns == NSTEPS);
      float* dp = lastL ? ypred : ((l & 1) ? wsb1 : wsb0);
      diffuse7_kernel<<<dim3(NWG), dim3(NTHR), 0, stream>>>(sp, dp, cv, ch,
                                                            source, mask, ns);
      sp = dp; done += ns; ++l;
    }
  } else {
    float* wsbuf = (float*)d_ws;
    dim3 grid(Ww / FT, Hh / FT, Bn);
    const float* sp = ybic;
    for (int it = 0; it < NSTEPS; ++it) {
      float* dp = (it & 1) ? ypred : wsbuf;
      step_kernel<<<grid, dim3(64), 0, stream>>>(sp, dp, cv, ch, source, mask);
      sp = dp;
    }
  }
}